// Round 15
// baseline (325.799 us; speedup 1.0000x reference)
//
#include <hip/hip_runtime.h>
#include <hip/hip_bf16.h>
#include <stdint.h>

#define DEV static __device__ __forceinline__

typedef __attribute__((ext_vector_type(8))) short bf16x8;
typedef __attribute__((ext_vector_type(4))) float f32x4;
typedef __attribute__((ext_vector_type(16))) float f32x16;

constexpr int Bc = 2, Sc = 2048, Dc = 2048;
constexpr int Hc = 16, HKVc = 4;
constexpr int RQc = 1024, RKVc = 512;
constexpr int DHc = 192, DRc = 64, DVc = 128;

DEV unsigned short f2bf(float f) {
  union { float f; uint32_t u; } v; v.f = f;
  uint32_t r = v.u + 0x7FFFu + ((v.u >> 16) & 1u);
  return (unsigned short)(r >> 16);
}
DEV float bf2f(unsigned short u) {
  union { uint32_t u; float f; } v; v.u = ((uint32_t)u) << 16;
  return v.f;
}

DEV void gload_lds16(const unsigned short* g, unsigned short* l) {
  __builtin_amdgcn_global_load_lds(
      (const __attribute__((address_space(1))) unsigned int*)g,
      (__attribute__((address_space(3))) unsigned int*)l, 16, 0, 0);
}

// ---------------- f32 -> bf16 conversion (vectorized) ----------------
__global__ void f2b_kernel(const float* __restrict__ in, unsigned short* __restrict__ out, int n) {
  int stride = gridDim.x * blockDim.x;
  for (int i = blockIdx.x * blockDim.x + threadIdx.x; i * 4 < n; i += stride) {
    float4 v = reinterpret_cast<const float4*>(in)[i];
    union { unsigned short u[4]; uint64_t q; } pk;
    pk.u[0] = f2bf(v.x); pk.u[1] = f2bf(v.y); pk.u[2] = f2bf(v.z); pk.u[3] = f2bf(v.w);
    reinterpret_cast<uint64_t*>(out)[i] = pk.q;
  }
}

// ---------------- weight transpose: in[R][C] f32 -> out[C][R] bf16 ----------------
__global__ void wtrans_kernel(const float* __restrict__ in, unsigned short* __restrict__ out,
                              int R, int C) {
  __shared__ float tile[32][33];
  const int c0 = blockIdx.x * 32, r0 = blockIdx.y * 32;
  const int tx = threadIdx.x & 31, ty = threadIdx.x >> 5;  // ty 0..7
#pragma unroll
  for (int i = 0; i < 32; i += 8)
    tile[ty + i][tx] = in[(size_t)(r0 + ty + i) * C + c0 + tx];
  __syncthreads();
#pragma unroll
  for (int i = 0; i < 32; i += 8)
    out[(size_t)(c0 + ty + i) * R + r0 + tx] = f2bf(tile[tx][ty + i]);
}

// ---------------- RoPE cos/sin table ----------------
__global__ void rope_table_kernel(float* __restrict__ cosT, float* __restrict__ sinT) {
  int idx = blockIdx.x * blockDim.x + threadIdx.x;
  if (idx >= Sc * DRc) return;
  int t = idx >> 6;
  int j = idx & 63;
  float inv = exp2f(-13.287712379549449f * (float)(j & 31) * (1.0f / 32.0f));
  float f = (float)t * inv;
  cosT[idx] = cosf(f);
  sinT[idx] = sinf(f);
}

// ---------------- RMSNorm (block per row), f32 in -> bf16 out ----------------
template<int R>
__global__ void rmsnorm_kernel(const float* __restrict__ in, int istride,
                               const float* __restrict__ g, unsigned short* __restrict__ out) {
  int row = blockIdx.x;
  const float* x = in + (size_t)row * istride;
  float ss = 0.f;
  for (int j = threadIdx.x; j < R; j += 256) { float v = x[j]; ss += v * v; }
  for (int off = 32; off; off >>= 1) ss += __shfl_down(ss, off, 64);
  __shared__ float wsum[4];
  if ((threadIdx.x & 63) == 0) wsum[threadIdx.x >> 6] = ss;
  __syncthreads();
  float tot = wsum[0] + wsum[1] + wsum[2] + wsum[3];
  float rs = rsqrtf(tot * (1.0f / R) + 1e-20f);
  for (int j = threadIdx.x; j < R; j += 256)
    out[(size_t)row * R + j] = f2bf(x[j] * rs * g[j]);
}

// ---------------- GEMM: C[M,N] = A[M,K] @ Bt[N,K]^T + bias (m97 single-buffer) ----------------
template<bool OUT_BF16, bool NG>
__global__ __launch_bounds__(256)
void gemm_tn_kernel(const unsigned short* __restrict__ A, const unsigned short* __restrict__ Bt,
                    const float* __restrict__ bias, void* __restrict__ Cout,
                    int M, int N, int K) {
  __shared__ __align__(16) unsigned short As[128 * 64];
  __shared__ __align__(16) unsigned short Bs[128 * 64];
  const int t = threadIdx.x, lane = t & 63, wave = t >> 6;
  const int wm = wave >> 1, wn = wave & 1;
  const int m0 = blockIdx.x * 128, n0 = blockIdx.y * 128;
  const int fr = lane & 15, fo = (lane >> 4) * 8, rg = lane >> 4;
  const int srow = lane >> 3;
  const int scol = (lane & 7) * 8;

  const unsigned short* Ap[4];
  const unsigned short* Bp[4];
#pragma unroll
  for (int i = 0; i < 4; ++i) {
    const int ar = m0 + wave * 32 + i * 8 + srow;
    Ap[i] = A + (size_t)ar * K + scol;
    int br = n0 + wave * 32 + i * 8 + srow;
    if (NG) br = br < N ? br : N - 1;
    Bp[i] = Bt + (size_t)br * K + scol;
  }

  f32x4 acc[4][4] = {};

  for (int k0 = 0; k0 < K; k0 += 64) {
    if (k0) __syncthreads();
#pragma unroll
    for (int i = 0; i < 4; ++i) {
      gload_lds16(Ap[i] + k0, &As[(wave * 32 + i * 8) * 64]);
      gload_lds16(Bp[i] + k0, &Bs[(wave * 32 + i * 8) * 64]);
    }
    asm volatile("s_waitcnt vmcnt(0)" ::: "memory");
    __syncthreads();
#pragma unroll
    for (int kk = 0; kk < 64; kk += 32) {
      bf16x8 af[4], bf[4];
#pragma unroll
      for (int m = 0; m < 4; ++m)
        af[m] = *reinterpret_cast<const bf16x8*>(&As[(wm * 64 + m * 16 + fr) * 64 + kk + fo]);
#pragma unroll
      for (int n = 0; n < 4; ++n)
        bf[n] = *reinterpret_cast<const bf16x8*>(&Bs[(wn * 64 + n * 16 + fr) * 64 + kk + fo]);
      __builtin_amdgcn_s_setprio(1);
#pragma unroll
      for (int m = 0; m < 4; ++m)
#pragma unroll
        for (int n = 0; n < 4; ++n)
          acc[m][n] = __builtin_amdgcn_mfma_f32_16x16x32_bf16(af[m], bf[n], acc[m][n], 0, 0, 0);
      __builtin_amdgcn_s_setprio(0);
    }
  }

#pragma unroll
  for (int m = 0; m < 4; ++m) {
    const int row = m0 + wm * 64 + m * 16 + rg * 4;
#pragma unroll
    for (int n = 0; n < 4; ++n) {
      const int col = n0 + wn * 64 + n * 16 + fr;
      if (NG && col >= N) continue;
      const float bb = bias[col];
#pragma unroll
      for (int r = 0; r < 4; ++r) {
        float v = acc[m][n][r] + bb;
        if (OUT_BF16)
          reinterpret_cast<unsigned short*>(Cout)[(size_t)(row + r) * N + col] = f2bf(v);
        else
          reinterpret_cast<float*>(Cout)[(size_t)(row + r) * N + col] = v;
      }
    }
  }
}

// ---------------- GEMM with fused Q epilogue (rope + scale + layout) ----------------
__global__ __launch_bounds__(256)
void gemm_qfuse_kernel(const unsigned short* __restrict__ A, const unsigned short* __restrict__ Bt,
                       const float* __restrict__ bias,
                       const float* __restrict__ cosT, const float* __restrict__ sinT,
                       unsigned short* __restrict__ Qt, int M, int N, int K) {
  const float QS = 0.07216878364870323f * 1.4426950408889634f;
  __shared__ __align__(16) unsigned short As[128 * 64];
  __shared__ __align__(16) unsigned short Bs[128 * 64];
  const int t = threadIdx.x, lane = t & 63, wave = t >> 6;
  const int wm = wave >> 1, wn = wave & 1;
  const int m0 = blockIdx.x * 128, n0 = blockIdx.y * 128;
  const int fr = lane & 15, fo = (lane >> 4) * 8, rg = lane >> 4;
  const int srow = lane >> 3;
  const int scol = (lane & 7) * 8;

  const unsigned short* Ap[4];
  const unsigned short* Bp[4];
#pragma unroll
  for (int i = 0; i < 4; ++i) {
    Ap[i] = A + (size_t)(m0 + wave * 32 + i * 8 + srow) * K + scol;
    Bp[i] = Bt + (size_t)(n0 + wave * 32 + i * 8 + srow) * K + scol;
  }

  f32x4 acc[4][4] = {};

  for (int k0 = 0; k0 < K; k0 += 64) {
    if (k0) __syncthreads();
#pragma unroll
    for (int i = 0; i < 4; ++i) {
      gload_lds16(Ap[i] + k0, &As[(wave * 32 + i * 8) * 64]);
      gload_lds16(Bp[i] + k0, &Bs[(wave * 32 + i * 8) * 64]);
    }
    asm volatile("s_waitcnt vmcnt(0)" ::: "memory");
    __syncthreads();
#pragma unroll
    for (int kk = 0; kk < 64; kk += 32) {
      bf16x8 af[4], bf[4];
#pragma unroll
      for (int m = 0; m < 4; ++m)
        af[m] = *reinterpret_cast<const bf16x8*>(&As[(wm * 64 + m * 16 + fr) * 64 + kk + fo]);
#pragma unroll
      for (int n = 0; n < 4; ++n)
        bf[n] = *reinterpret_cast<const bf16x8*>(&Bs[(wn * 64 + n * 16 + fr) * 64 + kk + fo]);
      __builtin_amdgcn_s_setprio(1);
#pragma unroll
      for (int m = 0; m < 4; ++m)
#pragma unroll
        for (int n = 0; n < 4; ++n)
          acc[m][n] = __builtin_amdgcn_mfma_f32_16x16x32_bf16(af[m], bf[n], acc[m][n], 0, 0, 0);
      __builtin_amdgcn_s_setprio(0);
    }
  }

  const int wbase = n0 + wn * 64;
  const int hq = wbase / 192;
  const int dbase = wbase - hq * 192;
  const bool ropewin = (dbase == 128);

#pragma unroll
  for (int m = 0; m < 4; ++m) {
    const int row0 = m0 + wm * 64 + m * 16 + rg * 4;
#pragma unroll
    for (int n = 0; n < 4; ++n) {
      const int col = wbase + n * 16 + fr;
      const int d = dbase + n * 16 + fr;
      const float bb = bias[col];
#pragma unroll
      for (int r = 0; r < 4; ++r) {
        const int row = row0 + r;
        const int s = row & (Sc - 1);
        const int bq = row >> 11;
        float qv = acc[m][n][r] + bb;
        if (ropewin) {
          const int j = d - 128;
          const int n2 = (n < 2) ? n + 2 : n - 2;
          const float pv = acc[m][n2][r] + bias[wbase + n2 * 16 + fr];
          const float c = cosT[s * 64 + j], sn = sinT[s * 64 + j];
          qv = (n < 2) ? (qv * c - pv * sn) : (qv * c + pv * sn);
        }
        Qt[((size_t)(bq * Hc + hq) * Sc + s) * DHc + d] = f2bf(qv * QS);
      }
    }
  }
}

// ---------------- prep K: chunk-major per 32-row tile ----------------
__global__ void prep_k_kernel(const unsigned short* __restrict__ kvb,
                              const float* __restrict__ ccat,
                              const float* __restrict__ cosT, const float* __restrict__ sinT,
                              unsigned short* __restrict__ K) {
  int bs = blockIdx.x;
  int s = bs & (Sc - 1);
  int b = bs >> 11;
  int d = threadIdx.x;
  if (d >= 192) return;
  unsigned short ropeval = 0;
  if (d >= 128) {
    int j = d - 128;
    float x = ccat[(size_t)bs * 1600 + 1536 + j];
    float other = ccat[(size_t)bs * 1600 + 1536 + (j < 32 ? j + 32 : j - 32)];
    float c = cosT[s * 64 + j], sn = sinT[s * 64 + j];
    float v = (j < 32) ? (x * c - other * sn) : (x * c + other * sn);
    ropeval = f2bf(v);
  }
  const size_t off = (size_t)(s >> 5) * 6144 + (d >> 3) * 256 + (s & 31) * 8 + (d & 7);
  for (int kvh = 0; kvh < HKVc; ++kvh) {
    unsigned short o;
    if (d < 128) o = kvb[(size_t)bs * 1024 + kvh * 256 + d];
    else o = ropeval;
    K[(size_t)(b * HKVc + kvh) * Sc * DHc + off] = o;
  }
}

// ---------------- V transpose -> chunk-major per 32-key tile ----------------
__global__ void vtrans_kernel(const unsigned short* __restrict__ kvb, unsigned short* __restrict__ Vt) {
  int idx = blockIdx.x;
  int dt = idx & 3;  idx >>= 2;
  int st = idx & 63; idx >>= 6;
  int kvh = idx & 3; idx >>= 2;
  int b = idx;
  __shared__ unsigned short tile[32][33];
  int t = threadIdx.x;
  int c = t & 31, r0 = t >> 5;
#pragma unroll
  for (int i = 0; i < 4; ++i) {
    int r = r0 + i * 8;
    int s = st * 32 + r;
    tile[r][c] = kvb[((size_t)(b * Sc + s)) * 1024 + kvh * 256 + 128 + dt * 32 + c];
  }
  __syncthreads();
#pragma unroll
  for (int i = 0; i < 4; ++i) {
    int r = r0 + i * 8;
    const int dd = dt * 32 + r;
    const int k = st * 32 + c;
    const size_t pos = (size_t)(k >> 5) * 4096 + ((k >> 3) & 3) * 1024 + dd * 8 + (k & 7);
    Vt[(size_t)((b * HKVc + kvh)) * DVc * Sc + pos] = tile[c][r];
  }
}

// ---------------- flash attention: split-KV across blocks ----------------
// 1536 blocks x 128 thr; bid%8=(b,kvh)->XCD pin; block = 2 waves = 2 heads.
// sub>=32 (q>=1024): TWO blocks per (g,hp,sub), kv-range halves [0,tmid)/[tmid,NT);
// each writes unnormalized f32 partials (O,m,l) -> merged by attn_merge_kernel
// (exact online-softmax algebra). sub<32: monolithic, direct write. Grid 1536
// = 6 blocks/CU (LDS 24KB) vs R13's 4 -> more TLP to hide the per-tile chain.
__global__ __launch_bounds__(128, 3)
void attn_kernel(const unsigned short* __restrict__ Q, const unsigned short* __restrict__ Kt,
                 const unsigned short* __restrict__ Vt, unsigned short* __restrict__ attnOut,
                 float* __restrict__ Opart, float* __restrict__ mlp) {
  __shared__ __align__(16) unsigned short Ks[2][6144];   // 2 x 12KB shared dbuf

  const int bid = blockIdx.x;
  const int g = bid & 7;
  const int b = g >> 2, kvh = g & 3;
  const int u = bid >> 3;                // 0..191
  int sub, hp, half; bool split;
  if (u < 128) {                         // split halves of big subs, big-first
    split = true; sub = 63 - (u >> 2); half = (u >> 1) & 1; hp = u & 1;
  } else {                               // monolithic small subs, big-first
    split = false; const int v = u - 128; sub = 31 - (v >> 1); hp = v & 1; half = 0;
  }
  const int w = threadIdx.x >> 6;        // 0..1
  const int h = kvh * 4 + hp * 2 + w;
  const int lane = threadIdx.x & 63;
  const int l31 = lane & 31, hi = lane >> 5;

  const unsigned short* Qh = Q + (size_t)(b * Hc + h) * Sc * DHc;
  const unsigned short* Kg = Kt + (size_t)(b * HKVc + kvh) * Sc * DHc;
  const unsigned short* Vg = Vt + (size_t)(b * HKVc + kvh) * DVc * Sc;

  const int q0 = sub * 32;
  const int q = q0 + l31;
  const int NT = sub + 1;
  const int tmid = (sub + 2) >> 1;       // ceil(NT/2)
  const int t0 = (split && half) ? tmid : 0;
  const int t1 = split ? (half ? NT : tmid) : NT;

  auto stage = [&](int t) {
    const unsigned short* src = Kg + (size_t)t * 6144;
    unsigned short* dst = &Ks[t & 1][0];
#pragma unroll
    for (int j = 0; j < 6; ++j) {
      const int jj = w * 6 + j;
      gload_lds16(src + jj * 512 + lane * 8, dst + jj * 512);
    }
  };

  bf16x8 qf[12];
#pragma unroll
  for (int f = 0; f < 12; ++f)
    qf[f] = *reinterpret_cast<const bf16x8*>(Qh + (size_t)q * DHc + f * 16 + hi * 8);

  f32x16 ot[4] = {};
  float m = -INFINITY, lsum = 0.f;

  stage(t0);
  asm volatile("s_waitcnt vmcnt(0)" ::: "memory");
  __syncthreads();

  for (int t = t0; t < t1; ++t) {
    const int cur = t & 1;

    bf16x8 vf[8];
#pragma unroll
    for (int dt = 0; dt < 4; ++dt)
#pragma unroll
      for (int k2 = 0; k2 < 2; ++k2)
        vf[dt * 2 + k2] = *reinterpret_cast<const bf16x8*>(
            Vg + (size_t)t * 4096 + (k2 * 2 + hi) * 1024 + (dt * 32 + l31) * 8);
    __builtin_amdgcn_sched_barrier(0);
    if (t + 1 < t1) stage(t + 1);
    __builtin_amdgcn_sched_barrier(0);

    const unsigned short* kb = &Ks[cur][0];
    f32x16 s = {};
    __builtin_amdgcn_s_setprio(1);
#pragma unroll
    for (int f = 0; f < 12; ++f) {
      bf16x8 kf = *reinterpret_cast<const bf16x8*>(kb + (f * 2 + hi) * 256 + l31 * 8);
      s = __builtin_amdgcn_mfma_f32_32x32x16_bf16(kf, qf[f], s, 0, 0, 0);
    }
    __builtin_amdgcn_s_setprio(0);

    float v[16];
    if (t == sub) {   // diagonal tile
#pragma unroll
      for (int rrr = 0; rrr < 16; ++rrr) {
        const int kl = (rrr & 3) + 8 * (rrr >> 2) + 4 * hi;
        v[rrr] = (kl <= l31) ? s[rrr] : -3.0e38f;
      }
    } else {
#pragma unroll
      for (int rrr = 0; rrr < 16; ++rrr) v[rrr] = s[rrr];
    }

    float pmax = fmaxf(fmaxf(fmaxf(v[0], v[1]), fmaxf(v[2], v[3])),
                       fmaxf(fmaxf(v[4], v[5]), fmaxf(v[6], v[7])));
    float pmax2 = fmaxf(fmaxf(fmaxf(v[8], v[9]), fmaxf(v[10], v[11])),
                        fmaxf(fmaxf(v[12], v[13]), fmaxf(v[14], v[15])));
    pmax = fmaxf(pmax, pmax2);
    pmax = fmaxf(pmax, __shfl_xor(pmax, 32, 64));

    float cf = 1.f;
    if (!__all(pmax - m <= 8.0f)) {   // defer-max (log2 units)
      const float mnew = fmaxf(m, pmax);
      cf = exp2f(m - mnew);
      m = mnew;
#pragma unroll
      for (int dt = 0; dt < 4; ++dt)
#pragma unroll
        for (int rrr = 0; rrr < 16; ++rrr) ot[dt][rrr] *= cf;
    }

    float pp[16];
    float rs = 0.f;
#pragma unroll
    for (int rrr = 0; rrr < 16; ++rrr) { pp[rrr] = exp2f(v[rrr] - m); rs += pp[rrr]; }
    rs += __shfl_xor(rs, 32, 64);
    lsum = lsum * cf + rs;

    uint32_t c[8], x[8];
#pragma unroll
    for (int ii = 0; ii < 8; ++ii) {
      asm("v_cvt_pk_bf16_f32 %0, %1, %2" : "=v"(c[ii]) : "v"(pp[2 * ii]), "v"(pp[2 * ii + 1]));
      x[ii] = (uint32_t)__shfl_xor((int)c[ii], 32, 64);
    }
    union { uint32_t w[4]; bf16x8 v8; } pa0, pa1;
    pa0.w[0] = hi ? x[2] : c[0];
    pa0.w[1] = hi ? x[3] : c[1];
    pa0.w[2] = hi ? c[2] : x[0];
    pa0.w[3] = hi ? c[3] : x[1];
    pa1.w[0] = hi ? x[6] : c[4];
    pa1.w[1] = hi ? x[7] : c[5];
    pa1.w[2] = hi ? c[6] : x[4];
    pa1.w[3] = hi ? c[7] : x[5];

    __builtin_amdgcn_s_setprio(1);
#pragma unroll
    for (int dt = 0; dt < 4; ++dt) {
      ot[dt] = __builtin_amdgcn_mfma_f32_32x32x16_bf16(vf[dt * 2], pa0.v8, ot[dt], 0, 0, 0);
      ot[dt] = __builtin_amdgcn_mfma_f32_32x32x16_bf16(vf[dt * 2 + 1], pa1.v8, ot[dt], 0, 0, 0);
    }
    __builtin_amdgcn_s_setprio(0);

    asm volatile("s_waitcnt vmcnt(0)" ::: "memory");
    __syncthreads();
  }

  if (!split) {
    const float inv = 1.0f / lsum;
    unsigned short* dst = attnOut + ((size_t)(b * Sc + q)) * (Hc * DVc) + h * DVc;
#pragma unroll
    for (int dt = 0; dt < 4; ++dt)
#pragma unroll
      for (int rq = 0; rq < 4; ++rq) {
        uint32_t lo = (uint32_t)f2bf(ot[dt][rq * 4 + 0] * inv) |
                      ((uint32_t)f2bf(ot[dt][rq * 4 + 1] * inv) << 16);
        uint32_t hi2 = (uint32_t)f2bf(ot[dt][rq * 4 + 2] * inv) |
                       ((uint32_t)f2bf(ot[dt][rq * 4 + 3] * inv) << 16);
        uint2 pk; pk.x = lo; pk.y = hi2;
        *reinterpret_cast<uint2*>(dst + dt * 32 + 8 * rq + 4 * hi) = pk;
      }
  } else {
    // unnormalized f32 partials; rowid = bh*1024 + (q-1024), q>=1024 guaranteed
    const int bh = b * Hc + h;
    const int rowid = (bh << 10) + (q - 1024);
    float* Op = Opart + ((size_t)(half * 32768 + rowid)) * 128;
#pragma unroll
    for (int dt = 0; dt < 4; ++dt)
#pragma unroll
      for (int rq = 0; rq < 4; ++rq) {
        float4 vv;
        vv.x = ot[dt][rq * 4 + 0];
        vv.y = ot[dt][rq * 4 + 1];
        vv.z = ot[dt][rq * 4 + 2];
        vv.w = ot[dt][rq * 4 + 3];
        *reinterpret_cast<float4*>(Op + dt * 32 + 8 * rq + 4 * hi) = vv;
      }
    if (hi == 0) {
      mlp[((size_t)half * 32768 + rowid) * 2] = m;
      mlp[((size_t)half * 32768 + rowid) * 2 + 1] = lsum;
    }
  }
}

// ---------------- merge split-KV partials (exact online-softmax algebra) ----------------
// 32768 rows (bh, q>=1024); 16 rows/block, 16 thr/row, 8 f32 each.
__global__ __launch_bounds__(256)
void attn_merge_kernel(const float* __restrict__ Opart, const float* __restrict__ mlp,
                       unsigned short* __restrict__ attnOut) {
  const int rowid = blockIdx.x * 16 + (threadIdx.x >> 4);
  const int dd = (threadIdx.x & 15) * 8;
  const int bh = rowid >> 10, qm = rowid & 1023;
  const int b = bh >> 4, h = bh & 15;
  const int q = 1024 + qm;
  const float m0 = mlp[(size_t)rowid * 2];
  const float l0 = mlp[(size_t)rowid * 2 + 1];
  const float m1 = mlp[((size_t)32768 + rowid) * 2];
  const float l1 = mlp[((size_t)32768 + rowid) * 2 + 1];
  const float ms = fmaxf(m0, m1);
  const float s0 = exp2f(m0 - ms), s1 = exp2f(m1 - ms);
  const float inv = 1.0f / (l0 * s0 + l1 * s1);
  const float* P0 = Opart + (size_t)rowid * 128 + dd;
  const float* P1 = Opart + ((size_t)32768 + rowid) * 128 + dd;
  float4 a0 = reinterpret_cast<const float4*>(P0)[0];
  float4 a1 = reinterpret_cast<const float4*>(P0)[1];
  float4 b0 = reinterpret_cast<const float4*>(P1)[0];
  float4 b1 = reinterpret_cast<const float4*>(P1)[1];
  union { unsigned short u[8]; uint4 v; } pk;
  pk.u[0] = f2bf((a0.x * s0 + b0.x * s1) * inv);
  pk.u[1] = f2bf((a0.y * s0 + b0.y * s1) * inv);
  pk.u[2] = f2bf((a0.z * s0 + b0.z * s1) * inv);
  pk.u[3] = f2bf((a0.w * s0 + b0.w * s1) * inv);
  pk.u[4] = f2bf((a1.x * s0 + b1.x * s1) * inv);
  pk.u[5] = f2bf((a1.y * s0 + b1.y * s1) * inv);
  pk.u[6] = f2bf((a1.z * s0 + b1.z * s1) * inv);
  pk.u[7] = f2bf((a1.w * s0 + b1.w * s1) * inv);
  *reinterpret_cast<uint4*>(attnOut + ((size_t)(b * Sc + q)) * (Hc * DVc) + h * DVc + dd) = pk.v;
}

// ---------------- host launch ----------------
extern "C" void kernel_launch(void* const* d_in, const int* in_sizes, int n_in,
                              void* d_out, int out_size, void* d_ws, size_t ws_size,
                              hipStream_t stream) {
  (void)in_sizes; (void)n_in; (void)out_size; (void)ws_size;
  const float* hidden = (const float*)d_in[0];
  const float* w_qa  = (const float*)d_in[2];
  const float* b_qa  = (const float*)d_in[3];
  const float* g_q   = (const float*)d_in[4];
  const float* w_qb  = (const float*)d_in[5];
  const float* b_qb  = (const float*)d_in[6];
  const float* w_kva = (const float*)d_in[7];
  const float* b_kva = (const float*)d_in[8];
  const float* g_kv  = (const float*)d_in[9];
  const float* w_kvb = (const float*)d_in[10];
  const float* b_kvb = (const float*)d_in[11];
  const float* w_o   = (const float*)d_in[12];
  const float* b_o   = (const float*)d_in[13];
  float* out = (float*)d_out;

  char* ws = (char*)d_ws;
  size_t off = 0;
  auto alloc = [&](size_t bytes) -> void* {
    void* p = ws + off;
    off += (bytes + 255) & ~(size_t)255;
    return p;
  };
  const int MS = Bc * Sc;  // 4096 rows
  const int NCAT = RQc + RKVc + DRc;  // 1600

  unsigned short* Xbf   = (unsigned short*)alloc((size_t)MS * Dc * 2);
  unsigned short* Wcat  = (unsigned short*)alloc((size_t)NCAT * Dc * 2);
  unsigned short* WqbT  = (unsigned short*)alloc((size_t)Hc * DHc * RQc * 2);
  unsigned short* WkvbT = (unsigned short*)alloc((size_t)HKVc * 256 * RKVc * 2);
  unsigned short* WoT   = (unsigned short*)alloc((size_t)Dc * Hc * DVc * 2);
  float* bcat = (float*)alloc((size_t)NCAT * 4);
  float* cosT = (float*)alloc((size_t)Sc * DRc * 4);
  float* sinT = (float*)alloc((size_t)Sc * DRc * 4);
  float* Ccat = (float*)alloc((size_t)MS * NCAT * 4);
  unsigned short* qan  = (unsigned short*)alloc((size_t)MS * RQc * 2);
  unsigned short* kvcn = (unsigned short*)alloc((size_t)MS * RKVc * 2);
  unsigned short* kvb  = (unsigned short*)alloc((size_t)MS * HKVc * 256 * 2);
  unsigned short* Qt   = (unsigned short*)alloc((size_t)Bc * Hc * Sc * DHc * 2);
  unsigned short* Kt   = (unsigned short*)alloc((size_t)Bc * HKVc * Sc * DHc * 2);
  unsigned short* Vt   = (unsigned short*)alloc((size_t)Bc * HKVc * DVc * Sc * 2);
  unsigned short* attnb= (unsigned short*)alloc((size_t)MS * Hc * DVc * 2);

  // split-KV partials: reuse Ccat+qan region (dead before attn).
  // Opart: 2 x 32768 x 128 f32 = 33.55 MB; mlp: 0.52 MB; fits in 34.6 MB.
  float* Opart = Ccat;
  float* mlp = Ccat + (size_t)2 * 32768 * 128;

  f2b_kernel<<<dim3(512), dim3(256), 0, stream>>>(hidden, Xbf, MS * Dc);
  wtrans_kernel<<<dim3(RQc / 32, Dc / 32), 256, 0, stream>>>(w_qa, Wcat, Dc, RQc);
  wtrans_kernel<<<dim3((RKVc + DRc) / 32, Dc / 32), 256, 0, stream>>>(w_kva, Wcat + (size_t)RQc * Dc, Dc, RKVc + DRc);
  wtrans_kernel<<<dim3(Hc * DHc / 32, RQc / 32), 256, 0, stream>>>(w_qb, WqbT, RQc, Hc * DHc);
  wtrans_kernel<<<dim3(HKVc * 256 / 32, RKVc / 32), 256, 0, stream>>>(w_kvb, WkvbT, RKVc, HKVc * 256);
  wtrans_kernel<<<dim3(Dc / 32, Hc * DVc / 32), 256, 0, stream>>>(w_o, WoT, Hc * DVc, Dc);
  hipMemcpyAsync(bcat, b_qa, (size_t)RQc * 4, hipMemcpyDeviceToDevice, stream);
  hipMemcpyAsync(bcat + RQc, b_kva, (size_t)(RKVc + DRc) * 4, hipMemcpyDeviceToDevice, stream);
  rope_table_kernel<<<dim3(512), dim3(256), 0, stream>>>(cosT, sinT);

  // fused q_a + kv_a: Ccat[4096][1600] = X @ Wcat^T + bcat
  gemm_tn_kernel<false, true><<<dim3(MS / 128, (NCAT + 127) / 128), 256, 0, stream>>>(Xbf, Wcat, bcat, Ccat, MS, NCAT, Dc);
  rmsnorm_kernel<1024><<<dim3(MS), 256, 0, stream>>>(Ccat, NCAT, g_q, qan);
  rmsnorm_kernel<512><<<dim3(MS), 256, 0, stream>>>(Ccat + RQc, NCAT, g_kv, kvcn);
  // q_b GEMM with fused rope/scale/layout epilogue -> Qt directly
  gemm_qfuse_kernel<<<dim3(MS / 128, Hc * DHc / 128), 256, 0, stream>>>(qan, WqbT, b_qb, cosT, sinT, Qt, MS, Hc * DHc, RQc);
  gemm_tn_kernel<true, false><<<dim3(MS / 128, HKVc * 256 / 128), 256, 0, stream>>>(kvcn, WkvbT, b_kvb, kvb, MS, HKVc * 256, RKVc);

  prep_k_kernel<<<dim3(MS), 256, 0, stream>>>(kvb, Ccat, cosT, sinT, Kt);
  vtrans_kernel<<<dim3(Bc * HKVc * (Sc / 32) * (DVc / 32)), 256, 0, stream>>>(kvb, Vt);

  attn_kernel<<<dim3(1536), dim3(128), 0, stream>>>(Qt, Kt, Vt, attnb, Opart, mlp);
  attn_merge_kernel<<<dim3(2048), dim3(256), 0, stream>>>(Opart, mlp, attnb);

  gemm_tn_kernel<false, false><<<dim3(MS / 128, Dc / 128), 256, 0, stream>>>(attnb, WoT, b_o, out, MS, Dc, Hc * DVc);
}

// Round 16
// 315.241 us; speedup vs baseline: 1.0335x; 1.0335x over previous
//
#include <hip/hip_runtime.h>
#include <hip/hip_bf16.h>
#include <stdint.h>

#define DEV static __device__ __forceinline__

typedef __attribute__((ext_vector_type(8))) short bf16x8;
typedef __attribute__((ext_vector_type(4))) float f32x4;
typedef __attribute__((ext_vector_type(16))) float f32x16;

constexpr int Bc = 2, Sc = 2048, Dc = 2048;
constexpr int Hc = 16, HKVc = 4;
constexpr int RQc = 1024, RKVc = 512;
constexpr int DHc = 192, DRc = 64, DVc = 128;

DEV unsigned short f2bf(float f) {
  union { float f; uint32_t u; } v; v.f = f;
  uint32_t r = v.u + 0x7FFFu + ((v.u >> 16) & 1u);
  return (unsigned short)(r >> 16);
}
DEV float bf2f(unsigned short u) {
  union { uint32_t u; float f; } v; v.u = ((uint32_t)u) << 16;
  return v.f;
}

DEV void gload_lds16(const unsigned short* g, unsigned short* l) {
  __builtin_amdgcn_global_load_lds(
      (const __attribute__((address_space(1))) unsigned int*)g,
      (__attribute__((address_space(3))) unsigned int*)l, 16, 0, 0);
}

// ---------------- f32 -> bf16 conversion (vectorized) ----------------
__global__ void f2b_kernel(const float* __restrict__ in, unsigned short* __restrict__ out, int n) {
  int stride = gridDim.x * blockDim.x;
  for (int i = blockIdx.x * blockDim.x + threadIdx.x; i * 4 < n; i += stride) {
    float4 v = reinterpret_cast<const float4*>(in)[i];
    union { unsigned short u[4]; uint64_t q; } pk;
    pk.u[0] = f2bf(v.x); pk.u[1] = f2bf(v.y); pk.u[2] = f2bf(v.z); pk.u[3] = f2bf(v.w);
    reinterpret_cast<uint64_t*>(out)[i] = pk.q;
  }
}

// ---------------- weight transpose: in[R][C] f32 -> out[C][R] bf16 ----------------
__global__ void wtrans_kernel(const float* __restrict__ in, unsigned short* __restrict__ out,
                              int R, int C) {
  __shared__ float tile[32][33];
  const int c0 = blockIdx.x * 32, r0 = blockIdx.y * 32;
  const int tx = threadIdx.x & 31, ty = threadIdx.x >> 5;  // ty 0..7
#pragma unroll
  for (int i = 0; i < 32; i += 8)
    tile[ty + i][tx] = in[(size_t)(r0 + ty + i) * C + c0 + tx];
  __syncthreads();
#pragma unroll
  for (int i = 0; i < 32; i += 8)
    out[(size_t)(c0 + ty + i) * R + r0 + tx] = f2bf(tile[tx][ty + i]);
}

// ---------------- RoPE cos/sin table ----------------
__global__ void rope_table_kernel(float* __restrict__ cosT, float* __restrict__ sinT) {
  int idx = blockIdx.x * blockDim.x + threadIdx.x;
  if (idx >= Sc * DRc) return;
  int t = idx >> 6;
  int j = idx & 63;
  float inv = exp2f(-13.287712379549449f * (float)(j & 31) * (1.0f / 32.0f));
  float f = (float)t * inv;
  cosT[idx] = cosf(f);
  sinT[idx] = sinf(f);
}

// ---------------- RMSNorm (block per row), f32 in -> bf16 out ----------------
template<int R>
__global__ void rmsnorm_kernel(const float* __restrict__ in, int istride,
                               const float* __restrict__ g, unsigned short* __restrict__ out) {
  int row = blockIdx.x;
  const float* x = in + (size_t)row * istride;
  float ss = 0.f;
  for (int j = threadIdx.x; j < R; j += 256) { float v = x[j]; ss += v * v; }
  for (int off = 32; off; off >>= 1) ss += __shfl_down(ss, off, 64);
  __shared__ float wsum[4];
  if ((threadIdx.x & 63) == 0) wsum[threadIdx.x >> 6] = ss;
  __syncthreads();
  float tot = wsum[0] + wsum[1] + wsum[2] + wsum[3];
  float rs = rsqrtf(tot * (1.0f / R) + 1e-20f);
  for (int j = threadIdx.x; j < R; j += 256)
    out[(size_t)row * R + j] = f2bf(x[j] * rs * g[j]);
}

// ---------------- GEMM: C[M,N] = A[M,K] @ Bt[N,K]^T + bias (m97 single-buffer) ----------------
template<bool OUT_BF16, bool NG>
__global__ __launch_bounds__(256)
void gemm_tn_kernel(const unsigned short* __restrict__ A, const unsigned short* __restrict__ Bt,
                    const float* __restrict__ bias, void* __restrict__ Cout,
                    int M, int N, int K) {
  __shared__ __align__(16) unsigned short As[128 * 64];
  __shared__ __align__(16) unsigned short Bs[128 * 64];
  const int t = threadIdx.x, lane = t & 63, wave = t >> 6;
  const int wm = wave >> 1, wn = wave & 1;
  const int m0 = blockIdx.x * 128, n0 = blockIdx.y * 128;
  const int fr = lane & 15, fo = (lane >> 4) * 8, rg = lane >> 4;
  const int srow = lane >> 3;
  const int scol = (lane & 7) * 8;

  const unsigned short* Ap[4];
  const unsigned short* Bp[4];
#pragma unroll
  for (int i = 0; i < 4; ++i) {
    const int ar = m0 + wave * 32 + i * 8 + srow;
    Ap[i] = A + (size_t)ar * K + scol;
    int br = n0 + wave * 32 + i * 8 + srow;
    if (NG) br = br < N ? br : N - 1;
    Bp[i] = Bt + (size_t)br * K + scol;
  }

  f32x4 acc[4][4] = {};

  for (int k0 = 0; k0 < K; k0 += 64) {
    if (k0) __syncthreads();
#pragma unroll
    for (int i = 0; i < 4; ++i) {
      gload_lds16(Ap[i] + k0, &As[(wave * 32 + i * 8) * 64]);
      gload_lds16(Bp[i] + k0, &Bs[(wave * 32 + i * 8) * 64]);
    }
    asm volatile("s_waitcnt vmcnt(0)" ::: "memory");
    __syncthreads();
#pragma unroll
    for (int kk = 0; kk < 64; kk += 32) {
      bf16x8 af[4], bf[4];
#pragma unroll
      for (int m = 0; m < 4; ++m)
        af[m] = *reinterpret_cast<const bf16x8*>(&As[(wm * 64 + m * 16 + fr) * 64 + kk + fo]);
#pragma unroll
      for (int n = 0; n < 4; ++n)
        bf[n] = *reinterpret_cast<const bf16x8*>(&Bs[(wn * 64 + n * 16 + fr) * 64 + kk + fo]);
      __builtin_amdgcn_s_setprio(1);
#pragma unroll
      for (int m = 0; m < 4; ++m)
#pragma unroll
        for (int n = 0; n < 4; ++n)
          acc[m][n] = __builtin_amdgcn_mfma_f32_16x16x32_bf16(af[m], bf[n], acc[m][n], 0, 0, 0);
      __builtin_amdgcn_s_setprio(0);
    }
  }

#pragma unroll
  for (int m = 0; m < 4; ++m) {
    const int row = m0 + wm * 64 + m * 16 + rg * 4;
#pragma unroll
    for (int n = 0; n < 4; ++n) {
      const int col = n0 + wn * 64 + n * 16 + fr;
      if (NG && col >= N) continue;
      const float bb = bias[col];
#pragma unroll
      for (int r = 0; r < 4; ++r) {
        float v = acc[m][n][r] + bb;
        if (OUT_BF16)
          reinterpret_cast<unsigned short*>(Cout)[(size_t)(row + r) * N + col] = f2bf(v);
        else
          reinterpret_cast<float*>(Cout)[(size_t)(row + r) * N + col] = v;
      }
    }
  }
}

// ---------------- GEMM with fused Q epilogue (rope + scale + layout) ----------------
__global__ __launch_bounds__(256)
void gemm_qfuse_kernel(const unsigned short* __restrict__ A, const unsigned short* __restrict__ Bt,
                       const float* __restrict__ bias,
                       const float* __restrict__ cosT, const float* __restrict__ sinT,
                       unsigned short* __restrict__ Qt, int M, int N, int K) {
  const float QS = 0.07216878364870323f * 1.4426950408889634f;
  __shared__ __align__(16) unsigned short As[128 * 64];
  __shared__ __align__(16) unsigned short Bs[128 * 64];
  const int t = threadIdx.x, lane = t & 63, wave = t >> 6;
  const int wm = wave >> 1, wn = wave & 1;
  const int m0 = blockIdx.x * 128, n0 = blockIdx.y * 128;
  const int fr = lane & 15, fo = (lane >> 4) * 8, rg = lane >> 4;
  const int srow = lane >> 3;
  const int scol = (lane & 7) * 8;

  const unsigned short* Ap[4];
  const unsigned short* Bp[4];
#pragma unroll
  for (int i = 0; i < 4; ++i) {
    Ap[i] = A + (size_t)(m0 + wave * 32 + i * 8 + srow) * K + scol;
    Bp[i] = Bt + (size_t)(n0 + wave * 32 + i * 8 + srow) * K + scol;
  }

  f32x4 acc[4][4] = {};

  for (int k0 = 0; k0 < K; k0 += 64) {
    if (k0) __syncthreads();
#pragma unroll
    for (int i = 0; i < 4; ++i) {
      gload_lds16(Ap[i] + k0, &As[(wave * 32 + i * 8) * 64]);
      gload_lds16(Bp[i] + k0, &Bs[(wave * 32 + i * 8) * 64]);
    }
    asm volatile("s_waitcnt vmcnt(0)" ::: "memory");
    __syncthreads();
#pragma unroll
    for (int kk = 0; kk < 64; kk += 32) {
      bf16x8 af[4], bf[4];
#pragma unroll
      for (int m = 0; m < 4; ++m)
        af[m] = *reinterpret_cast<const bf16x8*>(&As[(wm * 64 + m * 16 + fr) * 64 + kk + fo]);
#pragma unroll
      for (int n = 0; n < 4; ++n)
        bf[n] = *reinterpret_cast<const bf16x8*>(&Bs[(wn * 64 + n * 16 + fr) * 64 + kk + fo]);
      __builtin_amdgcn_s_setprio(1);
#pragma unroll
      for (int m = 0; m < 4; ++m)
#pragma unroll
        for (int n = 0; n < 4; ++n)
          acc[m][n] = __builtin_amdgcn_mfma_f32_16x16x32_bf16(af[m], bf[n], acc[m][n], 0, 0, 0);
      __builtin_amdgcn_s_setprio(0);
    }
  }

  const int wbase = n0 + wn * 64;
  const int hq = wbase / 192;
  const int dbase = wbase - hq * 192;
  const bool ropewin = (dbase == 128);

#pragma unroll
  for (int m = 0; m < 4; ++m) {
    const int row0 = m0 + wm * 64 + m * 16 + rg * 4;
#pragma unroll
    for (int n = 0; n < 4; ++n) {
      const int col = wbase + n * 16 + fr;
      const int d = dbase + n * 16 + fr;
      const float bb = bias[col];
#pragma unroll
      for (int r = 0; r < 4; ++r) {
        const int row = row0 + r;
        const int s = row & (Sc - 1);
        const int bq = row >> 11;
        float qv = acc[m][n][r] + bb;
        if (ropewin) {
          const int j = d - 128;
          const int n2 = (n < 2) ? n + 2 : n - 2;
          const float pv = acc[m][n2][r] + bias[wbase + n2 * 16 + fr];
          const float c = cosT[s * 64 + j], sn = sinT[s * 64 + j];
          qv = (n < 2) ? (qv * c - pv * sn) : (qv * c + pv * sn);
        }
        Qt[((size_t)(bq * Hc + hq) * Sc + s) * DHc + d] = f2bf(qv * QS);
      }
    }
  }
}

// ---------------- prep K: chunk-major per 32-row tile ----------------
__global__ void prep_k_kernel(const unsigned short* __restrict__ kvb,
                              const float* __restrict__ ccat,
                              const float* __restrict__ cosT, const float* __restrict__ sinT,
                              unsigned short* __restrict__ K) {
  int bs = blockIdx.x;
  int s = bs & (Sc - 1);
  int b = bs >> 11;
  int d = threadIdx.x;
  if (d >= 192) return;
  unsigned short ropeval = 0;
  if (d >= 128) {
    int j = d - 128;
    float x = ccat[(size_t)bs * 1600 + 1536 + j];
    float other = ccat[(size_t)bs * 1600 + 1536 + (j < 32 ? j + 32 : j - 32)];
    float c = cosT[s * 64 + j], sn = sinT[s * 64 + j];
    float v = (j < 32) ? (x * c - other * sn) : (x * c + other * sn);
    ropeval = f2bf(v);
  }
  const size_t off = (size_t)(s >> 5) * 6144 + (d >> 3) * 256 + (s & 31) * 8 + (d & 7);
  for (int kvh = 0; kvh < HKVc; ++kvh) {
    unsigned short o;
    if (d < 128) o = kvb[(size_t)bs * 1024 + kvh * 256 + d];
    else o = ropeval;
    K[(size_t)(b * HKVc + kvh) * Sc * DHc + off] = o;
  }
}

// ---------------- V transpose -> chunk-major per 32-key tile ----------------
__global__ void vtrans_kernel(const unsigned short* __restrict__ kvb, unsigned short* __restrict__ Vt) {
  int idx = blockIdx.x;
  int dt = idx & 3;  idx >>= 2;
  int st = idx & 63; idx >>= 6;
  int kvh = idx & 3; idx >>= 2;
  int b = idx;
  __shared__ unsigned short tile[32][33];
  int t = threadIdx.x;
  int c = t & 31, r0 = t >> 5;
#pragma unroll
  for (int i = 0; i < 4; ++i) {
    int r = r0 + i * 8;
    int s = st * 32 + r;
    tile[r][c] = kvb[((size_t)(b * Sc + s)) * 1024 + kvh * 256 + 128 + dt * 32 + c];
  }
  __syncthreads();
#pragma unroll
  for (int i = 0; i < 4; ++i) {
    int r = r0 + i * 8;
    const int dd = dt * 32 + r;
    const int k = st * 32 + c;
    const size_t pos = (size_t)(k >> 5) * 4096 + ((k >> 3) & 3) * 1024 + dd * 8 + (k & 7);
    Vt[(size_t)((b * HKVc + kvh)) * DVc * Sc + pos] = tile[c][r];
  }
}

// ---------------- flash attention: 64-key supersteps, half the barriers ----------------
// 1024 blocks x 128 thr; bid%8=(b,kvh)->XCD pin; block = 2 waves = 2 GQA heads
// on ONE 32-row q-subtile (R14 decomposition, big-first). K staged in 64-key
// supersteps (2x24KB dbuf = 48KB LDS): one vmcnt(0)+barrier per 64 keys instead
// of 32 -> per-iteration fixed cost amortized over 40 MFMAs (R15 showed TLP is
// NOT the limiter; fixed cost per iteration is). Inner 32-key half-steps are
// R9/R14's proven code verbatim; vf1 loaded lazily after half 0.
__global__ __launch_bounds__(128, 3)
void attn_kernel(const unsigned short* __restrict__ Q, const unsigned short* __restrict__ Kt,
                 const unsigned short* __restrict__ Vt, unsigned short* __restrict__ attnOut) {
  __shared__ __align__(16) unsigned short Ks[2][12288];   // 2 x 24KB (64-key supersteps)

  const int bid = blockIdx.x;
  const int g = bid & 7;
  const int b = g >> 2, kvh = g & 3;
  const int idx = bid >> 3;              // 0..127
  const int hp = idx & 1;
  const int sub = 63 - (idx >> 1);       // big subtiles first
  const int w = threadIdx.x >> 6;        // 0..1
  const int h = kvh * 4 + hp * 2 + w;
  const int lane = threadIdx.x & 63;
  const int l31 = lane & 31, hi = lane >> 5;

  const unsigned short* Qh = Q + (size_t)(b * Hc + h) * Sc * DHc;
  const unsigned short* Kg = Kt + (size_t)(b * HKVc + kvh) * Sc * DHc;
  const unsigned short* Vg = Vt + (size_t)(b * HKVc + kvh) * DVc * Sc;

  const int q0 = sub * 32;
  const int q = q0 + l31;
  const int NS = (sub >> 1) + 1;         // 64-key supersteps

  // stage superstep i = global 32-key tiles (2i, 2i+1), 24KB contiguous
  auto stage = [&](int i) {
    const unsigned short* src = Kg + (size_t)i * 12288;
    unsigned short* dst = &Ks[i & 1][0];
#pragma unroll
    for (int j = 0; j < 12; ++j) {
      const int jj = w * 12 + j;
      gload_lds16(src + jj * 512 + lane * 8, dst + jj * 512);
    }
  };

  bf16x8 qf[12];
#pragma unroll
  for (int f = 0; f < 12; ++f)
    qf[f] = *reinterpret_cast<const bf16x8*>(Qh + (size_t)q * DHc + f * 16 + hi * 8);

  f32x16 ot[4] = {};
  float m = -INFINITY, lsum = 0.f;

  // one 32-key half-step (R14's proven body)
  auto half_step = [&](const unsigned short* kb, int t, const bf16x8* vf) {
    f32x16 s = {};
    __builtin_amdgcn_s_setprio(1);
#pragma unroll
    for (int f = 0; f < 12; ++f) {
      bf16x8 kf = *reinterpret_cast<const bf16x8*>(kb + (f * 2 + hi) * 256 + l31 * 8);
      s = __builtin_amdgcn_mfma_f32_32x32x16_bf16(kf, qf[f], s, 0, 0, 0);
    }
    __builtin_amdgcn_s_setprio(0);

    float v[16];
    if (t == sub) {   // diagonal tile
#pragma unroll
      for (int rrr = 0; rrr < 16; ++rrr) {
        const int kl = (rrr & 3) + 8 * (rrr >> 2) + 4 * hi;
        v[rrr] = (kl <= l31) ? s[rrr] : -3.0e38f;
      }
    } else {
#pragma unroll
      for (int rrr = 0; rrr < 16; ++rrr) v[rrr] = s[rrr];
    }

    float pmax = fmaxf(fmaxf(fmaxf(v[0], v[1]), fmaxf(v[2], v[3])),
                       fmaxf(fmaxf(v[4], v[5]), fmaxf(v[6], v[7])));
    float pmax2 = fmaxf(fmaxf(fmaxf(v[8], v[9]), fmaxf(v[10], v[11])),
                        fmaxf(fmaxf(v[12], v[13]), fmaxf(v[14], v[15])));
    pmax = fmaxf(pmax, pmax2);
    pmax = fmaxf(pmax, __shfl_xor(pmax, 32, 64));

    float cf = 1.f;
    if (!__all(pmax - m <= 8.0f)) {   // defer-max (log2 units)
      const float mnew = fmaxf(m, pmax);
      cf = exp2f(m - mnew);
      m = mnew;
#pragma unroll
      for (int dt = 0; dt < 4; ++dt)
#pragma unroll
        for (int rrr = 0; rrr < 16; ++rrr) ot[dt][rrr] *= cf;
    }

    float pp[16];
    float rs = 0.f;
#pragma unroll
    for (int rrr = 0; rrr < 16; ++rrr) { pp[rrr] = exp2f(v[rrr] - m); rs += pp[rrr]; }
    rs += __shfl_xor(rs, 32, 64);
    lsum = lsum * cf + rs;

    uint32_t c[8], x[8];
#pragma unroll
    for (int ii = 0; ii < 8; ++ii) {
      asm("v_cvt_pk_bf16_f32 %0, %1, %2" : "=v"(c[ii]) : "v"(pp[2 * ii]), "v"(pp[2 * ii + 1]));
      x[ii] = (uint32_t)__shfl_xor((int)c[ii], 32, 64);
    }
    union { uint32_t w[4]; bf16x8 v8; } pa0, pa1;
    pa0.w[0] = hi ? x[2] : c[0];
    pa0.w[1] = hi ? x[3] : c[1];
    pa0.w[2] = hi ? c[2] : x[0];
    pa0.w[3] = hi ? c[3] : x[1];
    pa1.w[0] = hi ? x[6] : c[4];
    pa1.w[1] = hi ? x[7] : c[5];
    pa1.w[2] = hi ? c[6] : x[4];
    pa1.w[3] = hi ? c[7] : x[5];

    __builtin_amdgcn_s_setprio(1);
#pragma unroll
    for (int dt = 0; dt < 4; ++dt) {
      ot[dt] = __builtin_amdgcn_mfma_f32_32x32x16_bf16(vf[dt * 2], pa0.v8, ot[dt], 0, 0, 0);
      ot[dt] = __builtin_amdgcn_mfma_f32_32x32x16_bf16(vf[dt * 2 + 1], pa1.v8, ot[dt], 0, 0, 0);
    }
    __builtin_amdgcn_s_setprio(0);
  };

  stage(0);
  asm volatile("s_waitcnt vmcnt(0)" ::: "memory");
  __syncthreads();

  for (int i = 0; i < NS; ++i) {
    const int cur = i & 1;
    const int t0 = 2 * i;
    const bool has1 = (t0 + 1 <= sub);

    // V loads for half 0 FIRST (FIFO: PV's wait leaves the next stage in flight)
    bf16x8 vf0[8];
#pragma unroll
    for (int dt = 0; dt < 4; ++dt)
#pragma unroll
      for (int k2 = 0; k2 < 2; ++k2)
        vf0[dt * 2 + k2] = *reinterpret_cast<const bf16x8*>(
            Vg + (size_t)t0 * 4096 + (k2 * 2 + hi) * 1024 + (dt * 32 + l31) * 8);
    __builtin_amdgcn_sched_barrier(0);
    if (i + 1 < NS) stage(i + 1);
    __builtin_amdgcn_sched_barrier(0);

    half_step(&Ks[cur][0], t0, vf0);

    if (has1) {
      bf16x8 vf1[8];
#pragma unroll
      for (int dt = 0; dt < 4; ++dt)
#pragma unroll
        for (int k2 = 0; k2 < 2; ++k2)
          vf1[dt * 2 + k2] = *reinterpret_cast<const bf16x8*>(
              Vg + (size_t)(t0 + 1) * 4096 + (k2 * 2 + hi) * 1024 + (dt * 32 + l31) * 8);
      half_step(&Ks[cur][6144], t0 + 1, vf1);
    }

    asm volatile("s_waitcnt vmcnt(0)" ::: "memory");
    __syncthreads();
  }

  const float inv = 1.0f / lsum;
  unsigned short* dst = attnOut + ((size_t)(b * Sc + q)) * (Hc * DVc) + h * DVc;
#pragma unroll
  for (int dt = 0; dt < 4; ++dt)
#pragma unroll
    for (int rq = 0; rq < 4; ++rq) {
      uint32_t lo = (uint32_t)f2bf(ot[dt][rq * 4 + 0] * inv) |
                    ((uint32_t)f2bf(ot[dt][rq * 4 + 1] * inv) << 16);
      uint32_t hi2 = (uint32_t)f2bf(ot[dt][rq * 4 + 2] * inv) |
                     ((uint32_t)f2bf(ot[dt][rq * 4 + 3] * inv) << 16);
      uint2 pk; pk.x = lo; pk.y = hi2;
      *reinterpret_cast<uint2*>(dst + dt * 32 + 8 * rq + 4 * hi) = pk;
    }
}

// ---------------- host launch ----------------
extern "C" void kernel_launch(void* const* d_in, const int* in_sizes, int n_in,
                              void* d_out, int out_size, void* d_ws, size_t ws_size,
                              hipStream_t stream) {
  (void)in_sizes; (void)n_in; (void)out_size; (void)ws_size;
  const float* hidden = (const float*)d_in[0];
  const float* w_qa  = (const float*)d_in[2];
  const float* b_qa  = (const float*)d_in[3];
  const float* g_q   = (const float*)d_in[4];
  const float* w_qb  = (const float*)d_in[5];
  const float* b_qb  = (const float*)d_in[6];
  const float* w_kva = (const float*)d_in[7];
  const float* b_kva = (const float*)d_in[8];
  const float* g_kv  = (const float*)d_in[9];
  const float* w_kvb = (const float*)d_in[10];
  const float* b_kvb = (const float*)d_in[11];
  const float* w_o   = (const float*)d_in[12];
  const float* b_o   = (const float*)d_in[13];
  float* out = (float*)d_out;

  char* ws = (char*)d_ws;
  size_t off = 0;
  auto alloc = [&](size_t bytes) -> void* {
    void* p = ws + off;
    off += (bytes + 255) & ~(size_t)255;
    return p;
  };
  const int MS = Bc * Sc;  // 4096 rows
  const int NCAT = RQc + RKVc + DRc;  // 1600

  unsigned short* Xbf   = (unsigned short*)alloc((size_t)MS * Dc * 2);
  unsigned short* Wcat  = (unsigned short*)alloc((size_t)NCAT * Dc * 2);
  unsigned short* WqbT  = (unsigned short*)alloc((size_t)Hc * DHc * RQc * 2);
  unsigned short* WkvbT = (unsigned short*)alloc((size_t)HKVc * 256 * RKVc * 2);
  unsigned short* WoT   = (unsigned short*)alloc((size_t)Dc * Hc * DVc * 2);
  float* bcat = (float*)alloc((size_t)NCAT * 4);
  float* cosT = (float*)alloc((size_t)Sc * DRc * 4);
  float* sinT = (float*)alloc((size_t)Sc * DRc * 4);
  float* Ccat = (float*)alloc((size_t)MS * NCAT * 4);
  unsigned short* qan  = (unsigned short*)alloc((size_t)MS * RQc * 2);
  unsigned short* kvcn = (unsigned short*)alloc((size_t)MS * RKVc * 2);
  unsigned short* kvb  = (unsigned short*)alloc((size_t)MS * HKVc * 256 * 2);
  unsigned short* Qt   = (unsigned short*)alloc((size_t)Bc * Hc * Sc * DHc * 2);
  unsigned short* Kt   = (unsigned short*)alloc((size_t)Bc * HKVc * Sc * DHc * 2);
  unsigned short* Vt   = (unsigned short*)alloc((size_t)Bc * HKVc * DVc * Sc * 2);
  unsigned short* attnb= (unsigned short*)alloc((size_t)MS * Hc * DVc * 2);

  f2b_kernel<<<dim3(512), dim3(256), 0, stream>>>(hidden, Xbf, MS * Dc);
  wtrans_kernel<<<dim3(RQc / 32, Dc / 32), 256, 0, stream>>>(w_qa, Wcat, Dc, RQc);
  wtrans_kernel<<<dim3((RKVc + DRc) / 32, Dc / 32), 256, 0, stream>>>(w_kva, Wcat + (size_t)RQc * Dc, Dc, RKVc + DRc);
  wtrans_kernel<<<dim3(Hc * DHc / 32, RQc / 32), 256, 0, stream>>>(w_qb, WqbT, RQc, Hc * DHc);
  wtrans_kernel<<<dim3(HKVc * 256 / 32, RKVc / 32), 256, 0, stream>>>(w_kvb, WkvbT, RKVc, HKVc * 256);
  wtrans_kernel<<<dim3(Dc / 32, Hc * DVc / 32), 256, 0, stream>>>(w_o, WoT, Hc * DVc, Dc);
  hipMemcpyAsync(bcat, b_qa, (size_t)RQc * 4, hipMemcpyDeviceToDevice, stream);
  hipMemcpyAsync(bcat + RQc, b_kva, (size_t)(RKVc + DRc) * 4, hipMemcpyDeviceToDevice, stream);
  rope_table_kernel<<<dim3(512), dim3(256), 0, stream>>>(cosT, sinT);

  // fused q_a + kv_a: Ccat[4096][1600] = X @ Wcat^T + bcat
  gemm_tn_kernel<false, true><<<dim3(MS / 128, (NCAT + 127) / 128), 256, 0, stream>>>(Xbf, Wcat, bcat, Ccat, MS, NCAT, Dc);
  rmsnorm_kernel<1024><<<dim3(MS), 256, 0, stream>>>(Ccat, NCAT, g_q, qan);
  rmsnorm_kernel<512><<<dim3(MS), 256, 0, stream>>>(Ccat + RQc, NCAT, g_kv, kvcn);
  // q_b GEMM with fused rope/scale/layout epilogue -> Qt directly
  gemm_qfuse_kernel<<<dim3(MS / 128, Hc * DHc / 128), 256, 0, stream>>>(qan, WqbT, b_qb, cosT, sinT, Qt, MS, Hc * DHc, RQc);
  gemm_tn_kernel<true, false><<<dim3(MS / 128, HKVc * 256 / 128), 256, 0, stream>>>(kvcn, WkvbT, b_kvb, kvb, MS, HKVc * 256, RKVc);

  prep_k_kernel<<<dim3(MS), 256, 0, stream>>>(kvb, Ccat, cosT, sinT, Kt);
  vtrans_kernel<<<dim3(Bc * HKVc * (Sc / 32) * (DVc / 32)), 256, 0, stream>>>(kvb, Vt);

  attn_kernel<<<dim3(1024), dim3(128), 0, stream>>>(Qt, Kt, Vt, attnb);

  gemm_tn_kernel<false, false><<<dim3(MS / 128, Dc / 128), 256, 0, stream>>>(attnb, WoT, b_o, out, MS, Dc, Hc * DVc);
}